// Round 1
// baseline (223.988 us; speedup 1.0000x reference)
//
#include <hip/hip_runtime.h>

// Fused persistent-kernel version.
// 14-step recurrence, N=1680:
//   temp = J @ r_{t-1};  U = temp + Iext;  sq = (0.2U)^2
//   recSum = 0.005*sum(sq);  r_t = sq/recSum
// Carry unnormalized r̃_t = sq_t and s_t = recSum_t, so J@r_{t-1} = (J@r̃_{t-1})/s_{t-1}.
//
// Single kernel, 105 blocks x 256 threads (co-resident: 105 < 256 CUs).
// Each wave owns 4 rows; its J fragments live in VGPRs for all 14 steps
// (J read from HBM exactly once). Steps are separated by a hand-rolled
// device-scope barrier: release-atomicAdd on a per-step counter, relaxed
// spin + acquire fence on the consumer side. r̃ double-buffered; partials
// per-step (no ABA). Counters zeroed by a 64B hipMemsetAsync per launch.

#define N      1680
#define NV4    420          // N/4
#define NSTEP  14
#define GBLK   105          // blocks; 105*16 = 1680 rows
#define RPB    16           // rows per block
#define RPW    4            // rows per wave

__global__ __launch_bounds__(256, 1) void fused_recur(
    const float* __restrict__ J,
    const float* __restrict__ net_in,     // [0,N): Iext ; [N,2N): r0
    float* __restrict__ out,              // U_13 (N) | recSum_13 (1) | r_13 (N)
    float* __restrict__ ws)
{
    __shared__ float r_lds[N];
    __shared__ float sred[4];
    __shared__ float wsq[4];

    // ws layout (floats): [0,16): unsigned cnt[NSTEP] (zeroed per launch)
    //                     [16,1808): rbuf0  [1808,3600): rbuf1
    //                     [3600,...): partials[NSTEP][GBLK]
    unsigned* cnt = (unsigned*)ws;
    float* rbuf0    = ws + 16;
    float* rbuf1    = ws + 16 + 1792;
    float* partials = ws + 16 + 2 * 1792;

    const int tid  = threadIdx.x;
    const int lane = tid & 63;
    const int wave = tid >> 6;
    const int row0 = blockIdx.x * RPB + wave * RPW;

    // ---- prologue: pin J rows in VGPRs (J is read from HBM exactly once) ----
    float4 Jr[RPW][7];
    #pragma unroll
    for (int m = 0; m < RPW; ++m) {
        const float4* Jrow = (const float4*)(J + (size_t)(row0 + m) * N);
        #pragma unroll
        for (int k = 0; k < 7; ++k) {
            const int idx = lane + 64 * k;
            Jr[m][k] = (idx < NV4) ? Jrow[idx] : make_float4(0.f, 0.f, 0.f, 0.f);
        }
    }
    float iext[RPW];
    #pragma unroll
    for (int m = 0; m < RPW; ++m) iext[m] = net_in[row0 + m];

    float Uv[RPW], Qv[RPW];
    float4* rl4 = (float4*)r_lds;

    for (int t = 0; t < NSTEP; ++t) {
        float s_prev;
        if (t == 0) {
            // r0 straight from input; s_{-1} = 1 (r0 is already normalized)
            const float4* rs4 = (const float4*)(net_in + N);
            for (int i = tid; i < NV4; i += 256) rl4[i] = rs4[i];
            __syncthreads();
            s_prev = 1.0f;
        } else {
            // wait for all blocks to publish step t-1
            if (tid == 0) {
                while (__hip_atomic_load(&cnt[t - 1], __ATOMIC_RELAXED,
                                         __HIP_MEMORY_SCOPE_AGENT) < GBLK)
                    __builtin_amdgcn_s_sleep(1);
            }
            __syncthreads();   // also guarantees step t-1 LDS reads are done
            __threadfence();   // agent acquire: invalidate L1/L2 before re-reads

            const float* rsrc = (t & 1) ? rbuf0 : rbuf1;   // written at t-1
            const float4* rs4 = (const float4*)rsrc;
            for (int i = tid; i < NV4; i += 256) rl4[i] = rs4[i];

            // redundant per-block reduce of 105 partials -> s_{t-1}
            float p = 0.0f;
            if (tid < GBLK) p = partials[(t - 1) * GBLK + tid];
            #pragma unroll
            for (int off = 32; off; off >>= 1) p += __shfl_xor(p, off, 64);
            if (lane == 0) sred[wave] = p;
            __syncthreads();
            s_prev = sred[0] + sred[1] + sred[2] + sred[3];
        }

        // r̃ chunk LDS -> regs (shared across the wave's 4 rows)
        float4 rv[7];
        #pragma unroll
        for (int k = 0; k < 7; ++k) {
            const int idx = lane + 64 * k;
            rv[k] = (idx < NV4) ? rl4[idx] : make_float4(0.f, 0.f, 0.f, 0.f);
        }

        // 4 row-dots, then ILP'd butterfly reduce
        float a[RPW];
        #pragma unroll
        for (int m = 0; m < RPW; ++m) {
            float acc = 0.0f;
            #pragma unroll
            for (int k = 0; k < 7; ++k) {
                acc += Jr[m][k].x * rv[k].x;
                acc += Jr[m][k].y * rv[k].y;
                acc += Jr[m][k].z * rv[k].z;
                acc += Jr[m][k].w * rv[k].w;
            }
            a[m] = acc;
        }
        #pragma unroll
        for (int off = 32; off; off >>= 1) {
            #pragma unroll
            for (int m = 0; m < RPW; ++m) a[m] += __shfl_xor(a[m], off, 64);
        }

        float psum = 0.0f;
        #pragma unroll
        for (int m = 0; m < RPW; ++m) {
            const float U  = a[m] / s_prev + iext[m];   // ALPHA=BETA=1
            const float u2 = 0.2f * U;
            const float sq = u2 * u2;
            Uv[m] = U;
            Qv[m] = sq;
            psum += sq;
        }

        if (lane == 0) {
            wsq[wave] = 0.005f * psum;                  // K * sum(sq) partial
            if (t < NSTEP - 1) {
                float* wb = (t & 1) ? rbuf1 : rbuf0;
                *(float4*)(wb + row0) = make_float4(Qv[0], Qv[1], Qv[2], Qv[3]);
            }
        }
        __syncthreads();
        if (tid == 0) {
            partials[t * GBLK + blockIdx.x] = wsq[0] + wsq[1] + wsq[2] + wsq[3];
            // release: makes this block's r̃ stores + partial visible agent-wide
            __hip_atomic_fetch_add(&cnt[t], 1u, __ATOMIC_RELEASE,
                                   __HIP_MEMORY_SCOPE_AGENT);
        }
    }

    // ---- finish: s_13, then write U_13 | recSum_13 | r_13 ----
    if (tid == 0) {
        while (__hip_atomic_load(&cnt[NSTEP - 1], __ATOMIC_RELAXED,
                                 __HIP_MEMORY_SCOPE_AGENT) < GBLK)
            __builtin_amdgcn_s_sleep(1);
    }
    __syncthreads();
    __threadfence();
    float p = 0.0f;
    if (tid < GBLK) p = partials[(NSTEP - 1) * GBLK + tid];
    #pragma unroll
    for (int off = 32; off; off >>= 1) p += __shfl_xor(p, off, 64);
    if (lane == 0) sred[wave] = p;
    __syncthreads();
    const float s13 = sred[0] + sred[1] + sred[2] + sred[3];

    if (lane == 0)
        *(float4*)(out + row0) = make_float4(Uv[0], Uv[1], Uv[2], Uv[3]);
    if (lane < RPW) {
        const float q = (lane == 0) ? Qv[0] : (lane == 1) ? Qv[1]
                       : (lane == 2) ? Qv[2] : Qv[3];
        out[N + 1 + row0 + lane] = q / s13;             // r_13 = sq/recSum
    }
    if (blockIdx.x == 0 && tid == 0) out[N] = s13;      // recSum_13
}

extern "C" void kernel_launch(void* const* d_in, const int* in_sizes, int n_in,
                              void* d_out, int out_size, void* d_ws, size_t ws_size,
                              hipStream_t stream) {
    const float* net_in = (const float*)d_in[0];   // 2N: Iext | r0
    const float* J      = (const float*)d_in[1];   // N x N row-major
    // zero the per-step barrier counters (graph-capturable, 64 B)
    hipMemsetAsync(d_ws, 0, 64, stream);
    fused_recur<<<GBLK, 256, 0, stream>>>(J, net_in, (float*)d_out, (float*)d_ws);
}

// Round 2
// 130.798 us; speedup vs baseline: 1.7125x; 1.7125x over previous
//
#include <hip/hip_runtime.h>

// Fused persistent-kernel, FENCE-FREE cross-block protocol.
// 14-step recurrence, N=1680:
//   temp = J @ r_{t-1};  U = temp + Iext;  sq = (0.2U)^2
//   recSum = 0.005*sum(sq);  r_t = sq/recSum
// Carry unnormalized r̃_t = sq_t and s_t = recSum_t, so J@r_{t-1} = (J@r̃_{t-1})/s_{t-1}.
//
// Cross-block sync WITHOUT agent fences (buffer_wbl2/buffer_inv are the
// 11.8us/step killer seen in round 1): all shared data moves via RELAXED
// agent-scope atomics -> sc1-flagged loads/stores that write through /
// bypass the non-coherent per-XCD L2 and are coherent at the LLC.
// Ordering: __syncthreads() drains vmcnt(0) per wave, so
//   store r̃ (sc1) -> __syncthreads -> store partial (sc1)
// guarantees r̃ is LLC-visible before the partial is. The per-step partials
// array IS the barrier: memset to 0xBF bytes (-1.498f) per launch,
// producers write true partial (>= 0), consumers spin on v >= 0.

#define N      1680
#define NV4    420          // N/4
#define NSTEP  14
#define GBLK   105          // blocks; 105*16 = 1680 rows
#define RPB    16           // rows per block
#define RPW    4            // rows per wave

__device__ __forceinline__ float llc_load(const float* p) {
    return __hip_atomic_load(p, __ATOMIC_RELAXED, __HIP_MEMORY_SCOPE_AGENT);
}
__device__ __forceinline__ void llc_store(float* p, float v) {
    __hip_atomic_store(p, v, __ATOMIC_RELAXED, __HIP_MEMORY_SCOPE_AGENT);
}

__global__ __launch_bounds__(256, 1) void fused_recur(
    const float* __restrict__ J,
    const float* __restrict__ net_in,     // [0,N): Iext ; [N,2N): r0
    float* __restrict__ out,              // U_13 (N) | recSum_13 (1) | r_13 (N)
    float* __restrict__ ws)
{
    __shared__ float r_lds[N];
    __shared__ float sred[4];
    __shared__ float wsq[4];

    // ws layout (floats): [0,1470): partials[NSTEP][GBLK]  (memset 0xBF/launch)
    //                     [1472,3264): rbuf0   [3264,5056): rbuf1
    float* partials = ws;
    float* rbuf0    = ws + 1472;
    float* rbuf1    = ws + 1472 + 1792;

    const int tid  = threadIdx.x;
    const int lane = tid & 63;
    const int wave = tid >> 6;
    const int row0 = blockIdx.x * RPB + wave * RPW;

    // ---- prologue: pin J rows in VGPRs / L2 (read once, never invalidated) ----
    float4 Jr[RPW][7];
    #pragma unroll
    for (int m = 0; m < RPW; ++m) {
        const float4* Jrow = (const float4*)(J + (size_t)(row0 + m) * N);
        #pragma unroll
        for (int k = 0; k < 7; ++k) {
            const int idx = lane + 64 * k;
            Jr[m][k] = (idx < NV4) ? Jrow[idx] : make_float4(0.f, 0.f, 0.f, 0.f);
        }
    }
    float iext[RPW];
    #pragma unroll
    for (int m = 0; m < RPW; ++m) iext[m] = net_in[row0 + m];

    float Uv[RPW], Qv[RPW];
    float4* rl4 = (float4*)r_lds;

    for (int t = 0; t < NSTEP; ++t) {
        float s_prev;
        if (t == 0) {
            const float4* rs4 = (const float4*)(net_in + N);   // r0
            for (int i = tid; i < NV4; i += 256) rl4[i] = rs4[i];
            if (lane == 0) sred[wave] = 0.0f;
            __syncthreads();
            s_prev = 1.0f;
        } else {
            // --- barrier = poll step t-1 partials (sentinel -1.498f) ---
            const float* pp = partials + (t - 1) * GBLK;
            float v = 0.0f;
            if (tid < GBLK) {
                do { v = llc_load(pp + tid); } while (!(v >= 0.0f));
            }
            float p = v;
            #pragma unroll
            for (int off = 32; off; off >>= 1) p += __shfl_xor(p, off, 64);
            if (lane == 0) sred[wave] = p;                  // waves 2,3 write 0
            __syncthreads();   // gate: all partials observed -> r̃ is LLC-visible
            s_prev = sred[0] + sred[1] + sred[2] + sred[3];

            // --- stage r̃_{t-1} from LLC (sc1 scalar loads, bypass stale L1/L2) ---
            const float* rsrc = (t & 1) ? rbuf0 : rbuf1;    // written at t-1
            float rv_s[7];
            #pragma unroll
            for (int k = 0; k < 7; ++k) {
                const int idx = tid + 256 * k;
                rv_s[k] = (idx < N) ? llc_load(rsrc + idx) : 0.0f;
            }
            #pragma unroll
            for (int k = 0; k < 7; ++k) {
                const int idx = tid + 256 * k;
                if (idx < N) r_lds[idx] = rv_s[k];
            }
            __syncthreads();
        }

        // r̃ chunk LDS -> regs (shared across the wave's 4 rows)
        float4 rv[7];
        #pragma unroll
        for (int k = 0; k < 7; ++k) {
            const int idx = lane + 64 * k;
            rv[k] = (idx < NV4) ? rl4[idx] : make_float4(0.f, 0.f, 0.f, 0.f);
        }

        // 4 row-dots, ILP'd butterfly reduce
        float a[RPW];
        #pragma unroll
        for (int m = 0; m < RPW; ++m) {
            float acc = 0.0f;
            #pragma unroll
            for (int k = 0; k < 7; ++k) {
                acc += Jr[m][k].x * rv[k].x;
                acc += Jr[m][k].y * rv[k].y;
                acc += Jr[m][k].z * rv[k].z;
                acc += Jr[m][k].w * rv[k].w;
            }
            a[m] = acc;
        }
        #pragma unroll
        for (int off = 32; off; off >>= 1) {
            #pragma unroll
            for (int m = 0; m < RPW; ++m) a[m] += __shfl_xor(a[m], off, 64);
        }

        float psum = 0.0f;
        #pragma unroll
        for (int m = 0; m < RPW; ++m) {
            const float U  = a[m] / s_prev + iext[m];   // ALPHA=BETA=1
            const float u2 = 0.2f * U;
            const float sq = u2 * u2;
            Uv[m] = U;
            Qv[m] = sq;
            psum += sq;
        }

        if (lane == 0) {
            wsq[wave] = 0.005f * psum;                  // K * sum(sq) partial
            if (t < NSTEP - 1) {
                float* wb = (t & 1) ? rbuf1 : rbuf0;
                llc_store(wb + row0 + 0, Qv[0]);        // sc1: straight to LLC
                llc_store(wb + row0 + 1, Qv[1]);
                llc_store(wb + row0 + 2, Qv[2]);
                llc_store(wb + row0 + 3, Qv[3]);
            }
        }
        __syncthreads();   // drains vmcnt(0) per wave: r̃ stores are LLC-visible
        if (tid == 0) {
            llc_store(partials + t * GBLK + blockIdx.x,
                      wsq[0] + wsq[1] + wsq[2] + wsq[3]);   // publish = signal
        }
    }

    // ---- finish: poll step-13 partials, then write U_13 | recSum_13 | r_13 ----
    {
        const float* pp = partials + (NSTEP - 1) * GBLK;
        float v = 0.0f;
        if (tid < GBLK) {
            do { v = llc_load(pp + tid); } while (!(v >= 0.0f));
        }
        float p = v;
        #pragma unroll
        for (int off = 32; off; off >>= 1) p += __shfl_xor(p, off, 64);
        if (lane == 0) sred[wave] = p;
        __syncthreads();
    }
    const float s13 = sred[0] + sred[1] + sred[2] + sred[3];

    if (lane == 0)
        *(float4*)(out + row0) = make_float4(Uv[0], Uv[1], Uv[2], Uv[3]);
    if (lane < RPW) {
        const float q = (lane == 0) ? Qv[0] : (lane == 1) ? Qv[1]
                       : (lane == 2) ? Qv[2] : Qv[3];
        out[N + 1 + row0 + lane] = q / s13;             // r_13 = sq/recSum
    }
    if (blockIdx.x == 0 && tid == 0) out[N] = s13;      // recSum_13
}

extern "C" void kernel_launch(void* const* d_in, const int* in_sizes, int n_in,
                              void* d_out, int out_size, void* d_ws, size_t ws_size,
                              hipStream_t stream) {
    const float* net_in = (const float*)d_in[0];   // 2N: Iext | r0
    const float* J      = (const float*)d_in[1];   // N x N row-major
    // Sentinel-fill partials: every byte 0xBF -> each float = -1.498 (< 0).
    hipMemsetAsync(d_ws, 0xBF, NSTEP * GBLK * sizeof(float), stream);
    fused_recur<<<GBLK, 256, 0, stream>>>(J, net_in, (float*)d_out, (float*)d_ws);
}

// Round 3
// 109.350 us; speedup vs baseline: 2.0484x; 1.1961x over previous
//
#include <hip/hip_runtime.h>

// Fused persistent-kernel, ONE LLC round trip per step.
// 14-step recurrence, N=1680:
//   temp = J @ r_{t-1};  U = temp + Iext;  sq = (0.2U)^2
//   recSum = 0.005*sum(sq);  r_t = sq/recSum
// Invariant: carry unnormalized r̃_t = sq_t;  s_t = 0.005*sum(r̃_t);
//   J @ r_{t-1} = (J @ r̃_{t-1}) / s_{t-1}.
//
// Protocol: 14 per-step buffers (420 float4 each), sentinel-filled 0xBF
// (-1.498f) per launch. Producers write their sq quad with a write-through
// sc0|sc1 store; consumers poll the data elements directly (sq >= 0) with
// sc0|sc1 dwordx4 loads. The data IS the barrier: once a block has seen all
// 420 quads of step t-1, it has r̃_{t-1} in hand AND can compute s_{t-1}
// locally (0.005 * full sum) — no partials array, no fences, no vmcnt drain
// on the producer side (the next poll's vmcnt(0) covers it).

typedef float f32x4 __attribute__((ext_vector_type(4)));

#define N      1680
#define NV4    420          // N/4
#define NSTEP  14
#define GBLK   105          // blocks; 105*16 = 1680 rows
#define RPB    16           // rows per block
#define RPW    4            // rows per wave

__device__ __forceinline__ f32x4 llc_load4(const f32x4* p) {
    f32x4 v;
    asm volatile("global_load_dwordx4 %0, %1, off sc0 sc1\n\t"
                 "s_waitcnt vmcnt(0)"
                 : "=v"(v) : "v"(p) : "memory");
    return v;
}
__device__ __forceinline__ void llc_store4(f32x4* p, f32x4 v) {
    asm volatile("global_store_dwordx4 %0, %1, off sc0 sc1"
                 :: "v"(p), "v"(v) : "memory");
}

__global__ __launch_bounds__(256, 1) void fused_recur(
    const float* __restrict__ J,
    const float* __restrict__ net_in,     // [0,N): Iext ; [N,2N): r0
    float* __restrict__ out,              // U_13 (N) | recSum_13 (1) | r_13 (N)
    float* __restrict__ ws)               // 14 * 420 f32x4, sentinel-filled
{
    __shared__ f32x4 r_lds[NV4];
    __shared__ float sred[4];

    f32x4* bufs = (f32x4*)ws;

    const int tid  = threadIdx.x;
    const int lane = tid & 63;
    const int wave = tid >> 6;
    const int row0 = (int)blockIdx.x * RPB + wave * RPW;

    // ---- pin this wave's 4 J rows in VGPRs (112 regs), read from HBM once ----
    f32x4 Jr[RPW][7];
    #pragma unroll
    for (int m = 0; m < RPW; ++m) {
        const f32x4* Jrow = (const f32x4*)(J + (size_t)(row0 + m) * N);
        #pragma unroll
        for (int k = 0; k < 7; ++k) {
            const int idx = lane + 64 * k;
            Jr[m][k] = (idx < NV4) ? Jrow[idx] : (f32x4)0.f;
        }
    }
    // Forbid rematerialization of the J loads inside the t-loop.
    #pragma unroll
    for (int m = 0; m < RPW; ++m)
        #pragma unroll
        for (int k = 0; k < 7; ++k)
            asm volatile("" : "+v"(Jr[m][k]));

    float iext[RPW];
    #pragma unroll
    for (int m = 0; m < RPW; ++m) iext[m] = net_in[row0 + m];

    float Uv[RPW], Qv[RPW];

    // ---- stage r0 (t=0 input), s_{-1} = 1 ----
    {
        const f32x4* r0 = (const f32x4*)(net_in + N);
        for (int i = tid; i < NV4; i += 256) r_lds[i] = r0[i];
    }
    __syncthreads();
    float s_prev = 1.0f;

    #pragma unroll 1
    for (int t = 0; t < NSTEP; ++t) {
        if (t > 0) {
            // poll+stage step t-1 r̃ (data is the barrier), accumulate sum
            f32x4* src = bufs + (size_t)(t - 1) * NV4;
            f32x4 v0 = (f32x4)0.f, v1 = (f32x4)0.f;
            float psum;
            {
                const f32x4* p0 = src + tid;
                do { v0 = llc_load4(p0); }
                while (!(v0[0] >= 0.f && v0[1] >= 0.f &&
                         v0[2] >= 0.f && v0[3] >= 0.f));
                psum = (v0[0] + v0[1]) + (v0[2] + v0[3]);
            }
            const int i1 = tid + 256;
            if (i1 < NV4) {
                const f32x4* p1 = src + i1;
                do { v1 = llc_load4(p1); }
                while (!(v1[0] >= 0.f && v1[1] >= 0.f &&
                         v1[2] >= 0.f && v1[3] >= 0.f));
                psum += (v1[0] + v1[1]) + (v1[2] + v1[3]);
            }
            #pragma unroll
            for (int off = 32; off; off >>= 1) psum += __shfl_xor(psum, off, 64);
            if (lane == 0) sred[wave] = psum;
            r_lds[tid] = v0;
            if (i1 < NV4) r_lds[i1] = v1;
            __syncthreads();
            s_prev = 0.005f * ((sred[0] + sred[1]) + (sred[2] + sred[3]));
        }

        // r̃ fragments LDS -> regs (shared across the wave's 4 rows)
        f32x4 rv[7];
        #pragma unroll
        for (int k = 0; k < 7; ++k) {
            const int idx = lane + 64 * k;
            rv[k] = (idx < NV4) ? r_lds[idx] : (f32x4)0.f;
        }

        // 4 row-dots, ILP'd butterfly reduce
        float a[RPW];
        #pragma unroll
        for (int m = 0; m < RPW; ++m) {
            float acc = 0.f;
            #pragma unroll
            for (int k = 0; k < 7; ++k) {
                acc += Jr[m][k][0] * rv[k][0];
                acc += Jr[m][k][1] * rv[k][1];
                acc += Jr[m][k][2] * rv[k][2];
                acc += Jr[m][k][3] * rv[k][3];
            }
            a[m] = acc;
        }
        #pragma unroll
        for (int off = 32; off; off >>= 1) {
            #pragma unroll
            for (int m = 0; m < RPW; ++m) a[m] += __shfl_xor(a[m], off, 64);
        }

        #pragma unroll
        for (int m = 0; m < RPW; ++m) {
            const float U  = a[m] / s_prev + iext[m];   // ALPHA=BETA=1
            const float u2 = 0.2f * U;
            Uv[m] = U;
            Qv[m] = u2 * u2;                            // sq (always >= 0)
        }

        // publish this wave's 4 rows: the store IS the signal
        if (lane == 0) {
            f32x4 q4 = { Qv[0], Qv[1], Qv[2], Qv[3] };
            llc_store4(bufs + (size_t)t * NV4 + (row0 >> 2), q4);
        }
        __syncthreads();   // protect r_lds against next iteration's staging
    }

    // ---- finish: poll buf[13] to form s13, then write outputs ----
    {
        f32x4* src = bufs + (size_t)(NSTEP - 1) * NV4;
        f32x4 v0;
        float psum;
        {
            const f32x4* p0 = src + tid;
            do { v0 = llc_load4(p0); }
            while (!(v0[0] >= 0.f && v0[1] >= 0.f &&
                     v0[2] >= 0.f && v0[3] >= 0.f));
            psum = (v0[0] + v0[1]) + (v0[2] + v0[3]);
        }
        const int i1 = tid + 256;
        if (i1 < NV4) {
            const f32x4* p1 = src + i1;
            f32x4 v1;
            do { v1 = llc_load4(p1); }
            while (!(v1[0] >= 0.f && v1[1] >= 0.f &&
                     v1[2] >= 0.f && v1[3] >= 0.f));
            psum += (v1[0] + v1[1]) + (v1[2] + v1[3]);
        }
        #pragma unroll
        for (int off = 32; off; off >>= 1) psum += __shfl_xor(psum, off, 64);
        if (lane == 0) sred[wave] = psum;
        __syncthreads();
    }
    const float s13 = 0.005f * ((sred[0] + sred[1]) + (sred[2] + sred[3]));

    if (lane == 0) {
        f32x4 u4 = { Uv[0], Uv[1], Uv[2], Uv[3] };
        *(f32x4*)(out + row0) = u4;                     // U_13 (16B aligned)
    }
    if (lane < RPW) {                                   // r_13 (N+1 offset: scalar)
        const float q = (lane == 0) ? Qv[0] : (lane == 1) ? Qv[1]
                       : (lane == 2) ? Qv[2] : Qv[3];
        out[N + 1 + row0 + lane] = q / s13;
    }
    if (blockIdx.x == 0 && tid == 0) out[N] = s13;      // recSum_13
}

extern "C" void kernel_launch(void* const* d_in, const int* in_sizes, int n_in,
                              void* d_out, int out_size, void* d_ws, size_t ws_size,
                              hipStream_t stream) {
    const float* net_in = (const float*)d_in[0];   // 2N: Iext | r0
    const float* J      = (const float*)d_in[1];   // N x N row-major
    // Sentinel-fill all 14 step buffers: every byte 0xBF -> -1.498f (< 0).
    hipMemsetAsync(d_ws, 0xBF, (size_t)NSTEP * NV4 * sizeof(f32x4), stream);
    fused_recur<<<GBLK, 256, 0, stream>>>(J, net_in, (float*)d_out, (float*)d_ws);
}